// Round 1
// baseline (3468.356 us; speedup 1.0000x reference)
//
#include <hip/hip_runtime.h>
#include <cstddef>

#define TSTEPS 512
#define INDIM  22
#define HDIM   64
#define NBATCH 16                 // batch rows per block
#define KTOT   (INDIM + HDIM)    // 86 combined reduction dim
#define ZPAD   20                 // padded row stride (floats) for z buffer

__device__ __forceinline__ float sigm(float x) {
    return 1.0f / (1.0f + __expf(-x));
}
__device__ __forceinline__ float tanh_fast(float x) {
    // 1 - 2/(e^{2x}+1): stable for all x (inf -> 1, 0 -> -1)
    return 1.0f - 2.0f / (__expf(2.0f * x) + 1.0f);
}

// One block = 16 batch rows for all 512 timesteps.
// Thread (j = tid&63, q = tid>>6) computes gates {i,f,g,o} at h-index j for
// batches 4q..4q+3. Combined weight table WT[k][j][gate] in LDS (88 KB),
// z = [x(22) ; h(64)] double-buffered in LDS. One barrier per step.
__global__ __launch_bounds__(256, 1)
void lstm_fused(const float* __restrict__ x,     // [B, T, IN]
                const float* __restrict__ W_ih,  // [4H, IN]
                const float* __restrict__ W_hh,  // [4H, H]
                const float* __restrict__ b_ih,  // [4H]
                const float* __restrict__ b_hh,  // [4H]
                float* __restrict__ out)         // [B, T, H]
{
    __shared__ float WT[KTOT][HDIM][4];      // [k][j][gate] fp32, 88064 B
    __shared__ float zbuf[2][KTOT][ZPAD];    // [buf][k][batch(+pad)] 13760 B

    const int tid   = threadIdx.x;
    const int j     = tid & 63;
    const int q     = tid >> 6;              // wave id 0..3
    const int bbase = blockIdx.x * NBATCH;

    // ---- prologue: stage combined weights (this thread fills gate q*64+j) ----
    {
        const int gate = q * HDIM + j;
        const float* wi = W_ih + (size_t)gate * INDIM;
        #pragma unroll
        for (int k = 0; k < INDIM; ++k) WT[k][j][q] = wi[k];
        const float* wh = W_hh + (size_t)gate * HDIM;
        #pragma unroll
        for (int k = 0; k < HDIM; ++k) WT[INDIM + k][j][q] = wh[k];
    }
    // zero the h-region of buffer 0 (h_{-1} = 0); disjoint from x-region writes
    for (int idx = tid; idx < HDIM * NBATCH; idx += 256) {
        zbuf[0][INDIM + (idx >> 4)][idx & 15] = 0.0f;
    }
    // biases for this thread's 4 gates (time-invariant -> registers)
    const float bias0 = b_ih[0 * HDIM + j] + b_hh[0 * HDIM + j];
    const float bias1 = b_ih[1 * HDIM + j] + b_hh[1 * HDIM + j];
    const float bias2 = b_ih[2 * HDIM + j] + b_hh[2 * HDIM + j];
    const float bias3 = b_ih[3 * HDIM + j] + b_hh[3 * HDIM + j];

    // x staging map: s in [0, 352): b = s/22, i = s%22  (352 = 16*22 exactly)
    const int b0 = tid / INDIM, i0 = tid - b0 * INDIM;
    const int s1 = tid + 256;
    const int b1 = s1 / INDIM, i1 = s1 - b1 * INDIM;
    const bool has1 = (tid < NBATCH * INDIM - 256);   // tid < 96
    const float* xp0 = x + ((size_t)(bbase + b0) * TSTEPS) * INDIM + i0;
    const float* xp1 = x + ((size_t)(bbase + b1) * TSTEPS) * INDIM + i1;

    // stage x[t=0] into buffer 0
    zbuf[0][i0][b0] = *xp0;  xp0 += INDIM;
    if (has1) { zbuf[0][i1][b1] = *xp1; xp1 += INDIM; }

    float c[4] = {0.f, 0.f, 0.f, 0.f};
    float* op[4];
    #pragma unroll
    for (int bb = 0; bb < 4; ++bb)
        op[bb] = out + ((size_t)(bbase + 4 * q + bb) * TSTEPS) * HDIM + j;

    // LDS base pointers for vector access
    const float4* wrow = (const float4*)(&WT[0][0][0]) + j;        // + k*64
    const float4* zb0  = (const float4*)(&zbuf[0][0][0]) + q;      // + k*5
    const float4* zb1  = (const float4*)(&zbuf[1][0][0]) + q;

    for (int t = 0; t < TSTEPS; ++t) {
        const int cur = t & 1;
        const int nxt = cur ^ 1;
        __syncthreads();   // separates prev step's reads from this step's writes

        // stage x for t+1 into the other buffer (independent of this step's reads)
        if (t + 1 < TSTEPS) {
            zbuf[nxt][i0][b0] = *xp0;  xp0 += INDIM;
            if (has1) { zbuf[nxt][i1][b1] = *xp1; xp1 += INDIM; }
        }

        float acc[4][4];
        #pragma unroll
        for (int bb = 0; bb < 4; ++bb) {
            acc[bb][0] = bias0; acc[bb][1] = bias1;
            acc[bb][2] = bias2; acc[bb][3] = bias3;
        }

        const float4* zrow = cur ? zb1 : zb0;
        #pragma unroll
        for (int k = 0; k < KTOT; ++k) {
            const float4 w = wrow[k * 64];   // conflict-free b128: lanes j contiguous
            const float4 z = zrow[k * 5];    // wave-broadcast b128 (same addr all lanes)
            acc[0][0] += z.x * w.x; acc[0][1] += z.x * w.y;
            acc[0][2] += z.x * w.z; acc[0][3] += z.x * w.w;
            acc[1][0] += z.y * w.x; acc[1][1] += z.y * w.y;
            acc[1][2] += z.y * w.z; acc[1][3] += z.y * w.w;
            acc[2][0] += z.z * w.x; acc[2][1] += z.z * w.y;
            acc[2][2] += z.z * w.z; acc[2][3] += z.z * w.w;
            acc[3][0] += z.w * w.x; acc[3][1] += z.w * w.y;
            acc[3][2] += z.w * w.z; acc[3][3] += z.w * w.w;
        }

        // epilogue: gate nonlinearities, state update, h out (global + LDS)
        float hv[4];
        #pragma unroll
        for (int bb = 0; bb < 4; ++bb) {
            const float iv = sigm(acc[bb][0]);
            const float fv = sigm(acc[bb][1]);
            const float gv = tanh_fast(acc[bb][2]);
            const float ov = sigm(acc[bb][3]);
            c[bb] = fv * c[bb] + iv * gv;
            hv[bb] = ov * tanh_fast(c[bb]);
            *op[bb] = hv[bb];
            op[bb] += HDIM;
        }
        // h for next step: one b128 write per thread
        *(float4*)(&zbuf[nxt][INDIM + j][4 * q]) =
            make_float4(hv[0], hv[1], hv[2], hv[3]);
    }
}

extern "C" void kernel_launch(void* const* d_in, const int* in_sizes, int n_in,
                              void* d_out, int out_size, void* d_ws, size_t ws_size,
                              hipStream_t stream) {
    const float* x    = (const float*)d_in[0];
    const float* W_ih = (const float*)d_in[1];
    const float* W_hh = (const float*)d_in[2];
    const float* b_ih = (const float*)d_in[3];
    const float* b_hh = (const float*)d_in[4];
    float* out = (float*)d_out;

    const int B = in_sizes[0] / (TSTEPS * INDIM);   // 4096
    const int grid = B / NBATCH;                    // 256 blocks, 1 per CU
    lstm_fused<<<grid, 256, 0, stream>>>(x, W_ih, W_hh, b_ih, b_hh, out);
}